// Round 2
// baseline (524.019 us; speedup 1.0000x reference)
//
#include <hip/hip_runtime.h>
#include <stdint.h>
#include <stddef.h>

#define NB  64
#define ND  256
#define NLC 1024
#define NLQ 128
#define INVKEEP (1.0f/0.9f)

// ---- workspace layout (float offsets); total 14,835,712 floats = 56.6 MiB ----
#define OFF_SQ    0u            // NB*NLQ          = 8192
#define OFF_RMAX  8192u         // NB*NLC          = 65536  (row max of S)
#define OFF_RSUM  73728u        // NB*NLC          = 65536  (RECIPROCAL row sum)
#define OFF_CMAX  139264u       // NB*NLQ          = 8192   (col max)
#define OFF_CSUM  147456u       // NB*NLQ          = 8192   (RECIPROCAL col sum)
#define OFF_S     155648u       // NB*NLC*NLQ      = 8388608 (raw S)
#define OFF_M     8544256u      // 2*NB*ND*NLQ     = 4194304 (split-K partial M)
#define OFF_MASK  12738560u     // N/32 u32 words  = 2097152 (dropout bitmask)

// ================= threefry2x32, key = (0,42) (jax.random.key(42)) =========
__device__ __forceinline__ void tf_round(uint32_t& a, uint32_t& b, const int r) {
  a += b;
  b = (b << r) | (b >> (32 - r));
  b ^= a;
}

// JAX threefry_partitionable, 32-bit path: counts are uint64 flat indices,
// split as (x0=hi32(n)=0, x1=lo32(n)=n); for bit_width<64 the result is
// convert_element_type(bits1 ^ bits2) — XOR of BOTH output words.
__device__ __forceinline__ uint32_t threefry_xor(uint32_t x0, uint32_t x1) {
  const uint32_t ks0 = 0u, ks1 = 42u, ks2 = 0x1BD11BDAu ^ 0u ^ 42u;
  x0 += ks0; x1 += ks1;
  tf_round(x0,x1,13); tf_round(x0,x1,15); tf_round(x0,x1,26); tf_round(x0,x1,6);
  x0 += ks1; x1 += ks2 + 1u;
  tf_round(x0,x1,17); tf_round(x0,x1,29); tf_round(x0,x1,16); tf_round(x0,x1,24);
  x0 += ks2; x1 += ks0 + 2u;
  tf_round(x0,x1,13); tf_round(x0,x1,15); tf_round(x0,x1,26); tf_round(x0,x1,6);
  x0 += ks0; x1 += ks1 + 3u;
  tf_round(x0,x1,17); tf_round(x0,x1,29); tf_round(x0,x1,16); tf_round(x0,x1,24);
  x0 += ks1; x1 += ks2 + 4u;
  tf_round(x0,x1,13); tf_round(x0,x1,15); tf_round(x0,x1,26); tf_round(x0,x1,6);
  x0 += ks2; x1 += ks0 + 5u;
  return x0 ^ x1;
}

// dropout mask: bit n of the 2^26-element tensor, packed 32/word
__global__ __launch_bounds__(256) void k_mask(uint32_t* __restrict__ mask) {
  const uint32_t t = blockIdx.x * 256u + threadIdx.x;   // word index
  const uint32_t base = t << 5;
  uint32_t w = 0u;
  #pragma unroll 4
  for (int k = 0; k < 32; ++k) {
    const uint32_t bits = threefry_xor(0u, base + (uint32_t)k);
    const float u = __uint_as_float((bits >> 9) | 0x3f800000u) - 1.0f;
    w |= (u < 0.9f ? 1u : 0u) << k;
  }
  mask[t] = w;
}

// ================= sq[b,j] = sum_d wq[d] * Q[b,d,j] ==========================
__global__ __launch_bounds__(128) void k_sq(const float* __restrict__ Q,
                                            const float* __restrict__ W,
                                            float* __restrict__ ws) {
  const int b = blockIdx.x;
  const int j = threadIdx.x;
  const float* wq = W + (size_t)b*768;
  const float* Qb = Q + (size_t)b*ND*NLQ;
  float acc = 0.0f;
  for (int d = 0; d < ND; ++d) acc = fmaf(wq[d], Qb[(size_t)d*NLQ + j], acc);
  ws[OFF_SQ + (size_t)b*NLQ + j] = acc;
}

// ========== S[b,i,j] = sum_d C[d,i]*(wm[d]*Q[d,j]+wc[d]) + sq[j] ============
// block: (i-tile of 64) x (all 128 j); fuses row-softmax stats.
__global__ __launch_bounds__(256) void k_s(const float* __restrict__ C,
                                           const float* __restrict__ Q,
                                           const float* __restrict__ W,
                                           float* __restrict__ ws) {
  __shared__ float Cs[32][64];
  __shared__ float Qs[32][128];
  __shared__ float wmS[256], wcS[256], sqS[128];
  const int b  = blockIdx.y;
  const int i0 = blockIdx.x * 64;
  const int t  = threadIdx.x;
  const int jg = t & 15;        // j = jg*8 .. +7
  const int ig = t >> 4;        // i = i0 + ig*4 .. +3
  wcS[t] = W[(size_t)b*768 + 256 + t];
  wmS[t] = W[(size_t)b*768 + 512 + t];
  if (t < 128) sqS[t] = ws[OFF_SQ + (size_t)b*NLQ + t];

  float acc[4][8];
  #pragma unroll
  for (int r = 0; r < 4; ++r)
    #pragma unroll
    for (int x = 0; x < 8; ++x) acc[r][x] = 0.0f;

  const float* Cb = C + (size_t)b*ND*NLC;
  const float* Qb = Q + (size_t)b*ND*NLQ;

  for (int d0 = 0; d0 < ND; d0 += 32) {
    __syncthreads();
    #pragma unroll
    for (int r = 0; r < 2; ++r) {           // stage C tile [32 d][64 i]
      const int f = r*256 + t;
      const int dk = f >> 4, i4 = f & 15;
      *(float4*)&Cs[dk][i4*4] = *(const float4*)&Cb[(size_t)(d0+dk)*NLC + i0 + i4*4];
    }
    #pragma unroll
    for (int r = 0; r < 4; ++r) {           // stage Q' = wm*Q + wc  [32 d][128 j]
      const int f = r*256 + t;
      const int dk = f >> 5, j4 = f & 31;
      const float4 qv = *(const float4*)&Qb[(size_t)(d0+dk)*NLQ + j4*4];
      const float wmv = wmS[d0+dk], wcv = wcS[d0+dk];
      float4 o;
      o.x = fmaf(wmv, qv.x, wcv);
      o.y = fmaf(wmv, qv.y, wcv);
      o.z = fmaf(wmv, qv.z, wcv);
      o.w = fmaf(wmv, qv.w, wcv);
      *(float4*)&Qs[dk][j4*4] = o;
    }
    __syncthreads();
    #pragma unroll
    for (int dk = 0; dk < 32; ++dk) {
      const float4 cq = *(const float4*)&Cs[dk][ig*4];
      const float4 q0 = *(const float4*)&Qs[dk][jg*8];
      const float4 q1 = *(const float4*)&Qs[dk][jg*8+4];
      const float cr[4] = {cq.x, cq.y, cq.z, cq.w};
      const float qv[8] = {q0.x,q0.y,q0.z,q0.w,q1.x,q1.y,q1.z,q1.w};
      #pragma unroll
      for (int r = 0; r < 4; ++r)
        #pragma unroll
        for (int x = 0; x < 8; ++x)
          acc[r][x] = fmaf(cr[r], qv[x], acc[r][x]);
    }
  }

  float sqv[8];
  #pragma unroll
  for (int x = 0; x < 8; ++x) sqv[x] = sqS[jg*8 + x];
  float* Sb = ws + OFF_S + ((size_t)b*NLC + (size_t)i0)*NLQ;
  #pragma unroll
  for (int r = 0; r < 4; ++r) {
    float sv[8];
    #pragma unroll
    for (int x = 0; x < 8; ++x) sv[x] = acc[r][x] + sqv[x];
    float m = sv[0];
    #pragma unroll
    for (int x = 1; x < 8; ++x) m = fmaxf(m, sv[x]);
    m = fmaxf(m, __shfl_xor(m, 1));   // row = 16 contiguous lanes (jg)
    m = fmaxf(m, __shfl_xor(m, 2));
    m = fmaxf(m, __shfl_xor(m, 4));
    m = fmaxf(m, __shfl_xor(m, 8));
    float s = 0.0f;
    #pragma unroll
    for (int x = 0; x < 8; ++x) s += __expf(sv[x] - m);
    s += __shfl_xor(s, 1);
    s += __shfl_xor(s, 2);
    s += __shfl_xor(s, 4);
    s += __shfl_xor(s, 8);
    const int row = ig*4 + r;
    *(float4*)&Sb[(size_t)row*NLQ + jg*8]     = make_float4(sv[0],sv[1],sv[2],sv[3]);
    *(float4*)&Sb[(size_t)row*NLQ + jg*8 + 4] = make_float4(sv[4],sv[5],sv[6],sv[7]);
    if (jg == 0) {
      ws[OFF_RMAX + (size_t)b*NLC + i0 + row] = m;
      ws[OFF_RSUM + (size_t)b*NLC + i0 + row] = 1.0f / s;
    }
  }
}

// ============ column softmax stats over i (axis=1): cmax, 1/csum ============
__global__ __launch_bounds__(256) void k_colstats(float* __restrict__ ws) {
  __shared__ float red[8][32];
  const int b  = blockIdx.y;
  const int jq = blockIdx.x;            // 4 j-quarters of 32
  const int tx = threadIdx.x & 31;
  const int ty = threadIdx.x >> 5;      // 8 i-strips of 128
  const int j  = jq*32 + tx;
  const float* Sb = ws + OFF_S + (size_t)b*NLC*NLQ;
  float m = -3.0e38f;
  for (int ii = 0; ii < 128; ++ii)
    m = fmaxf(m, Sb[(size_t)(ty*128 + ii)*NLQ + j]);
  red[ty][tx] = m;
  __syncthreads();
  if (ty == 0) {
    #pragma unroll
    for (int y = 1; y < 8; ++y) m = fmaxf(m, red[y][tx]);
    red[0][tx] = m;
  }
  __syncthreads();
  const float cm = red[0][tx];
  __syncthreads();
  float s = 0.0f;
  for (int ii = 0; ii < 128; ++ii)
    s += __expf(Sb[(size_t)(ty*128 + ii)*NLQ + j] - cm);
  red[ty][tx] = s;
  __syncthreads();
  if (ty == 0) {
    #pragma unroll
    for (int y = 1; y < 8; ++y) s += red[y][tx];
    ws[OFF_CMAX + (size_t)b*NLQ + j] = cm;
    ws[OFF_CSUM + (size_t)b*NLQ + j] = 1.0f / s;
  }
}

// ======= M[b,d,j] = sum_k C[b,d,k] * S__[b,k,j]  (split-K=2 partials) =======
__global__ __launch_bounds__(256) void k_m(const float* __restrict__ C,
                                           float* __restrict__ ws) {
  __shared__ float Ps[32][128];
  __shared__ float Csh[32][132];        // [kk][d], padded
  __shared__ float cmS[128], icS[128];
  const int b   = blockIdx.y;
  const int dh  = blockIdx.x & 1;       // d half: 128 rows
  const int ksp = blockIdx.x >> 1;      // k split: 512 each
  const int t   = threadIdx.x;
  const int jg  = t & 15;               // j = jg*8..+7
  const int dg  = t >> 4;               // d = dh*128 + dg*8..+7
  if (t < 128) {
    cmS[t] = ws[OFF_CMAX + (size_t)b*NLQ + t];
    icS[t] = ws[OFF_CSUM + (size_t)b*NLQ + t];   // reciprocal
  }
  float acc[8][8];
  #pragma unroll
  for (int r = 0; r < 8; ++r)
    #pragma unroll
    for (int x = 0; x < 8; ++x) acc[r][x] = 0.0f;

  const float* Cb = C + (size_t)b*ND*NLC + (size_t)dh*128*NLC;
  const float* Sb = ws + OFF_S + (size_t)b*NLC*NLQ;
  const int kbase = ksp * 512;

  for (int kt = 0; kt < 16; ++kt) {
    const int k0 = kbase + kt*32;
    __syncthreads();
    #pragma unroll
    for (int r = 0; r < 4; ++r) {       // stage S__ tile, exp applied
      const int f = r*256 + t;
      const int kk = f >> 5, j4 = f & 31;
      const float4 sv = *(const float4*)&Sb[(size_t)(k0+kk)*NLQ + j4*4];
      const int j = j4*4;
      float4 p;
      p.x = __expf(sv.x - cmS[j+0]) * icS[j+0];
      p.y = __expf(sv.y - cmS[j+1]) * icS[j+1];
      p.z = __expf(sv.z - cmS[j+2]) * icS[j+2];
      p.w = __expf(sv.w - cmS[j+3]) * icS[j+3];
      *(float4*)&Ps[kk][j4*4] = p;
    }
    #pragma unroll
    for (int r = 0; r < 4; ++r) {       // stage C transposed -> [kk][d]
      const int f = r*256 + t;
      const int kq = f & 7, dl = f >> 3;
      const float4 cv = *(const float4*)&Cb[(size_t)dl*NLC + k0 + kq*4];
      Csh[kq*4+0][dl] = cv.x;
      Csh[kq*4+1][dl] = cv.y;
      Csh[kq*4+2][dl] = cv.z;
      Csh[kq*4+3][dl] = cv.w;
    }
    __syncthreads();
    #pragma unroll
    for (int kk = 0; kk < 32; ++kk) {
      const float4 c0 = *(const float4*)&Csh[kk][dg*8];
      const float4 c1 = *(const float4*)&Csh[kk][dg*8+4];
      const float4 p0 = *(const float4*)&Ps[kk][jg*8];
      const float4 p1 = *(const float4*)&Ps[kk][jg*8+4];
      const float cr[8] = {c0.x,c0.y,c0.z,c0.w,c1.x,c1.y,c1.z,c1.w};
      const float pv[8] = {p0.x,p0.y,p0.z,p0.w,p1.x,p1.y,p1.z,p1.w};
      #pragma unroll
      for (int r = 0; r < 8; ++r)
        #pragma unroll
        for (int x = 0; x < 8; ++x)
          acc[r][x] = fmaf(cr[r], pv[x], acc[r][x]);
    }
  }
  float* Mp = ws + OFF_M + ((size_t)ksp*NB + b)*ND*NLQ + (size_t)dh*128*NLQ;
  #pragma unroll
  for (int r = 0; r < 8; ++r) {
    const int d = dg*8 + r;
    *(float4*)&Mp[(size_t)d*NLQ + jg*8]     = make_float4(acc[r][0],acc[r][1],acc[r][2],acc[r][3]);
    *(float4*)&Mp[(size_t)d*NLQ + jg*8 + 4] = make_float4(acc[r][4],acc[r][5],acc[r][6],acc[r][7]);
  }
}

// ==== final: A = Q*S_^T, Bm = M*S_^T, write [C, A, C*A, C*Bm] w/ dropout ====
// block: (b, i-tile 128, d-group 64). LDS = 128 KiB (transposed [j][.] tiles).
__global__ __launch_bounds__(256) void k_final(const float* __restrict__ C,
                                               const float* __restrict__ Q,
                                               float* __restrict__ ws,
                                               float* __restrict__ out) {
  __shared__ float St[128][128];        // [j][i]  S_ row-softmaxed
  __shared__ float Qt[128][64];         // [j][d]
  __shared__ float Mt[128][64];         // [j][d]  M0+M1
  const int b  = blockIdx.z;
  const int i0 = blockIdx.x * 128;
  const int d0 = blockIdx.y * 64;
  const int t  = threadIdx.x;
  const int ig = t & 15;                // i = i0 + ig*8 .. +7
  const int dg = t >> 4;                // d = d0 + dg*4 .. +3

  const float* Sb  = ws + OFF_S + ((size_t)b*NLC + (size_t)i0)*NLQ;
  const float* rmp = ws + OFF_RMAX + (size_t)b*NLC + i0;
  const float* irp = ws + OFF_RSUM + (size_t)b*NLC + i0;
  #pragma unroll
  for (int r = 0; r < 16; ++r) {        // stage S_ transposed, exp applied
    const int f = r*256 + t;
    const int il = f & 127, j4 = f >> 7;
    const float4 sv = *(const float4*)&Sb[(size_t)il*NLQ + j4*4];
    const float rm = rmp[il];
    const float ir = irp[il];           // reciprocal row sum
    St[j4*4+0][il] = __expf(sv.x - rm) * ir;
    St[j4*4+1][il] = __expf(sv.y - rm) * ir;
    St[j4*4+2][il] = __expf(sv.z - rm) * ir;
    St[j4*4+3][il] = __expf(sv.w - rm) * ir;
  }
  const float* Qb  = Q + (size_t)b*ND*NLQ + (size_t)d0*NLQ;
  const float* M0p = ws + OFF_M + (size_t)b*ND*NLQ + (size_t)d0*NLQ;
  const float* M1p = M0p + (size_t)NB*ND*NLQ;
  #pragma unroll
  for (int r = 0; r < 8; ++r) {         // stage Q, M transposed
    const int f = r*256 + t;
    const int dl = f & 63, j4 = f >> 6;
    const float4 qv = *(const float4*)&Qb[(size_t)dl*NLQ + j4*4];
    Qt[j4*4+0][dl] = qv.x; Qt[j4*4+1][dl] = qv.y;
    Qt[j4*4+2][dl] = qv.z; Qt[j4*4+3][dl] = qv.w;
    const float4 m0 = *(const float4*)&M0p[(size_t)dl*NLQ + j4*4];
    const float4 m1 = *(const float4*)&M1p[(size_t)dl*NLQ + j4*4];
    Mt[j4*4+0][dl] = m0.x + m1.x; Mt[j4*4+1][dl] = m0.y + m1.y;
    Mt[j4*4+2][dl] = m0.z + m1.z; Mt[j4*4+3][dl] = m0.w + m1.w;
  }
  __syncthreads();

  float accA[4][8], accB[4][8];
  #pragma unroll
  for (int r = 0; r < 4; ++r)
    #pragma unroll
    for (int x = 0; x < 8; ++x) { accA[r][x] = 0.0f; accB[r][x] = 0.0f; }

  #pragma unroll 2
  for (int j = 0; j < 128; ++j) {
    const float4 s0 = *(const float4*)&St[j][ig*8];
    const float4 s1 = *(const float4*)&St[j][ig*8+4];
    const float4 q4 = *(const float4*)&Qt[j][dg*4];
    const float4 m4 = *(const float4*)&Mt[j][dg*4];
    const float sv[8] = {s0.x,s0.y,s0.z,s0.w,s1.x,s1.y,s1.z,s1.w};
    const float qv[4] = {q4.x,q4.y,q4.z,q4.w};
    const float mv[4] = {m4.x,m4.y,m4.z,m4.w};
    #pragma unroll
    for (int r = 0; r < 4; ++r)
      #pragma unroll
      for (int x = 0; x < 8; ++x) {
        accA[r][x] = fmaf(qv[r], sv[x], accA[r][x]);
        accB[r][x] = fmaf(mv[r], sv[x], accB[r][x]);
      }
  }

  const float* Cb = C + (size_t)b*ND*NLC;
  const uint32_t* mw = (const uint32_t*)(ws + OFF_MASK);
  #pragma unroll
  for (int r = 0; r < 4; ++r) {
    const int d = d0 + dg*4 + r;
    const int i = i0 + ig*8;
    const float4 cc0 = *(const float4*)&Cb[(size_t)d*NLC + i];
    const float4 cc1 = *(const float4*)&Cb[(size_t)d*NLC + i + 4];
    const float cv[8] = {cc0.x,cc0.y,cc0.z,cc0.w,cc1.x,cc1.y,cc1.z,cc1.w};
    #pragma unroll
    for (int s = 0; s < 4; ++s) {
      const uint32_t ch = (uint32_t)(s*ND + d);
      const uint32_t nbase = ((((uint32_t)b << 10) + ch) << 10) + (uint32_t)i;
      const uint32_t wbits = mw[nbase >> 5];
      const uint32_t sh = nbase & 31u;
      float ov[8];
      #pragma unroll
      for (int x = 0; x < 8; ++x) {
        float v;
        if (s == 0)      v = cv[x];
        else if (s == 1) v = accA[r][x];
        else if (s == 2) v = cv[x] * accA[r][x];
        else             v = cv[x] * accB[r][x];
        ov[x] = ((wbits >> (sh + (uint32_t)x)) & 1u) ? v * INVKEEP : 0.0f;
      }
      *(float4*)&out[nbase]     = make_float4(ov[0],ov[1],ov[2],ov[3]);
      *(float4*)&out[nbase + 4] = make_float4(ov[4],ov[5],ov[6],ov[7]);
    }
  }
}

extern "C" void kernel_launch(void* const* d_in, const int* in_sizes, int n_in,
                              void* d_out, int out_size, void* d_ws, size_t ws_size,
                              hipStream_t stream) {
  (void)in_sizes; (void)n_in; (void)out_size; (void)ws_size;
  const float* C = (const float*)d_in[0];
  const float* Q = (const float*)d_in[1];
  const float* W = (const float*)d_in[2];
  float* out = (float*)d_out;
  float* ws  = (float*)d_ws;
  uint32_t* mask = (uint32_t*)(ws + OFF_MASK);

  hipLaunchKernelGGL(k_sq,       dim3(NB),       dim3(128), 0, stream, Q, W, ws);
  hipLaunchKernelGGL(k_mask,     dim3(8192),     dim3(256), 0, stream, mask);
  hipLaunchKernelGGL(k_s,        dim3(16, NB),   dim3(256), 0, stream, C, Q, W, ws);
  hipLaunchKernelGGL(k_colstats, dim3(4, NB),    dim3(256), 0, stream, ws);
  hipLaunchKernelGGL(k_m,        dim3(4, NB),    dim3(256), 0, stream, C, ws);
  hipLaunchKernelGGL(k_final,    dim3(8, 4, NB), dim3(256), 0, stream, C, Q, ws, out);
}

// Round 3
// 491.017 us; speedup vs baseline: 1.0672x; 1.0672x over previous
//
#include <hip/hip_runtime.h>
#include <stdint.h>
#include <stddef.h>

#define NB  64
#define ND  256
#define NLC 1024
#define NLQ 128
#define INVKEEP (1.0f/0.9f)

// ---- workspace layout (float offsets); total 14,835,712 floats = 56.6 MiB ----
#define OFF_SQ    0u            // NB*NLQ          = 8192
#define OFF_RMAX  8192u         // NB*NLC          = 65536  (row max of S)
#define OFF_RSUM  73728u        // NB*NLC          = 65536  (RECIPROCAL row sum)
#define OFF_CMAX  139264u       // NB*NLQ          = 8192   (col max)
#define OFF_CSUM  147456u       // NB*NLQ          = 8192   (RECIPROCAL col sum)
#define OFF_S     155648u       // NB*NLC*NLQ      = 8388608 (raw S)
#define OFF_M     8544256u      // 2*NB*ND*NLQ     = 4194304 (split-K partial M)
#define OFF_MASK  12738560u     // N/32 u32 words  = 2097152 (dropout bitmask)

// bf16 helpers: RNE pack, cheap unpack of a packed pair (lo = even index)
__device__ __forceinline__ uint32_t f2bf(float x) {
  const uint32_t u = __float_as_uint(x);
  return (u + 0x7fffu + ((u >> 16) & 1u)) >> 16;
}
__device__ __forceinline__ float bflo(uint32_t p) { return __uint_as_float(p << 16); }
__device__ __forceinline__ float bfhi(uint32_t p) { return __uint_as_float(p & 0xffff0000u); }

// ================= threefry2x32, key = (0,42) (jax.random.key(42)) =========
__device__ __forceinline__ void tf_round(uint32_t& a, uint32_t& b, const int r) {
  a += b;
  b = (b << r) | (b >> (32 - r));
  b ^= a;
}

// JAX threefry_partitionable 32-bit path: bits = o0 ^ o1 (verified round 2)
__device__ __forceinline__ uint32_t threefry_xor(uint32_t x0, uint32_t x1) {
  const uint32_t ks0 = 0u, ks1 = 42u, ks2 = 0x1BD11BDAu ^ 0u ^ 42u;
  x0 += ks0; x1 += ks1;
  tf_round(x0,x1,13); tf_round(x0,x1,15); tf_round(x0,x1,26); tf_round(x0,x1,6);
  x0 += ks1; x1 += ks2 + 1u;
  tf_round(x0,x1,17); tf_round(x0,x1,29); tf_round(x0,x1,16); tf_round(x0,x1,24);
  x0 += ks2; x1 += ks0 + 2u;
  tf_round(x0,x1,13); tf_round(x0,x1,15); tf_round(x0,x1,26); tf_round(x0,x1,6);
  x0 += ks0; x1 += ks1 + 3u;
  tf_round(x0,x1,17); tf_round(x0,x1,29); tf_round(x0,x1,16); tf_round(x0,x1,24);
  x0 += ks1; x1 += ks2 + 4u;
  tf_round(x0,x1,13); tf_round(x0,x1,15); tf_round(x0,x1,26); tf_round(x0,x1,6);
  x0 += ks2; x1 += ks0 + 5u;
  return x0 ^ x1;
}

__global__ __launch_bounds__(256) void k_mask(uint32_t* __restrict__ mask) {
  const uint32_t t = blockIdx.x * 256u + threadIdx.x;   // word index
  const uint32_t base = t << 5;
  uint32_t w = 0u;
  #pragma unroll 4
  for (int k = 0; k < 32; ++k) {
    const uint32_t bits = threefry_xor(0u, base + (uint32_t)k);
    const float u = __uint_as_float((bits >> 9) | 0x3f800000u) - 1.0f;
    w |= (u < 0.9f ? 1u : 0u) << k;
  }
  mask[t] = w;
}

// ================= sq[b,j] = sum_d wq[d] * Q[b,d,j] ==========================
__global__ __launch_bounds__(128) void k_sq(const float* __restrict__ Q,
                                            const float* __restrict__ W,
                                            float* __restrict__ ws) {
  const int b = blockIdx.x;
  const int j = threadIdx.x;
  const float* wq = W + (size_t)b*768;
  const float* Qb = Q + (size_t)b*ND*NLQ;
  float acc = 0.0f;
  for (int d = 0; d < ND; ++d) acc = fmaf(wq[d], Qb[(size_t)d*NLQ + j], acc);
  ws[OFF_SQ + (size_t)b*NLQ + j] = acc;
}

// ========== S[b,i,j] = sum_d C[d,i]*(wm[d]*Q[d,j]+wc[d]) + sq[j] ============
__global__ __launch_bounds__(256) void k_s(const float* __restrict__ C,
                                           const float* __restrict__ Q,
                                           const float* __restrict__ W,
                                           float* __restrict__ ws) {
  __shared__ float Cs[32][64];
  __shared__ float Qs[32][128];
  __shared__ float wmS[256], wcS[256], sqS[128];
  const int b  = blockIdx.y;
  const int i0 = blockIdx.x * 64;
  const int t  = threadIdx.x;
  const int jg = t & 15;        // j = jg*8 .. +7
  const int ig = t >> 4;        // i = i0 + ig*4 .. +3
  wcS[t] = W[(size_t)b*768 + 256 + t];
  wmS[t] = W[(size_t)b*768 + 512 + t];
  if (t < 128) sqS[t] = ws[OFF_SQ + (size_t)b*NLQ + t];

  float acc[4][8];
  #pragma unroll
  for (int r = 0; r < 4; ++r)
    #pragma unroll
    for (int x = 0; x < 8; ++x) acc[r][x] = 0.0f;

  const float* Cb = C + (size_t)b*ND*NLC;
  const float* Qb = Q + (size_t)b*ND*NLQ;

  for (int d0 = 0; d0 < ND; d0 += 32) {
    __syncthreads();
    #pragma unroll
    for (int r = 0; r < 2; ++r) {           // stage C tile [32 d][64 i]
      const int f = r*256 + t;
      const int dk = f >> 4, i4 = f & 15;
      *(float4*)&Cs[dk][i4*4] = *(const float4*)&Cb[(size_t)(d0+dk)*NLC + i0 + i4*4];
    }
    #pragma unroll
    for (int r = 0; r < 4; ++r) {           // stage Q' = wm*Q + wc  [32 d][128 j]
      const int f = r*256 + t;
      const int dk = f >> 5, j4 = f & 31;
      const float4 qv = *(const float4*)&Qb[(size_t)(d0+dk)*NLQ + j4*4];
      const float wmv = wmS[d0+dk], wcv = wcS[d0+dk];
      float4 o;
      o.x = fmaf(wmv, qv.x, wcv);
      o.y = fmaf(wmv, qv.y, wcv);
      o.z = fmaf(wmv, qv.z, wcv);
      o.w = fmaf(wmv, qv.w, wcv);
      *(float4*)&Qs[dk][j4*4] = o;
    }
    __syncthreads();
    #pragma unroll
    for (int dk = 0; dk < 32; ++dk) {
      const float4 cq = *(const float4*)&Cs[dk][ig*4];
      const float4 q0 = *(const float4*)&Qs[dk][jg*8];
      const float4 q1 = *(const float4*)&Qs[dk][jg*8+4];
      const float cr[4] = {cq.x, cq.y, cq.z, cq.w};
      const float qv[8] = {q0.x,q0.y,q0.z,q0.w,q1.x,q1.y,q1.z,q1.w};
      #pragma unroll
      for (int r = 0; r < 4; ++r)
        #pragma unroll
        for (int x = 0; x < 8; ++x)
          acc[r][x] = fmaf(cr[r], qv[x], acc[r][x]);
    }
  }

  float sqv[8];
  #pragma unroll
  for (int x = 0; x < 8; ++x) sqv[x] = sqS[jg*8 + x];
  float* Sb = ws + OFF_S + ((size_t)b*NLC + (size_t)i0)*NLQ;
  #pragma unroll
  for (int r = 0; r < 4; ++r) {
    float sv[8];
    #pragma unroll
    for (int x = 0; x < 8; ++x) sv[x] = acc[r][x] + sqv[x];
    float m = sv[0];
    #pragma unroll
    for (int x = 1; x < 8; ++x) m = fmaxf(m, sv[x]);
    m = fmaxf(m, __shfl_xor(m, 1));   // row = 16 contiguous lanes (jg)
    m = fmaxf(m, __shfl_xor(m, 2));
    m = fmaxf(m, __shfl_xor(m, 4));
    m = fmaxf(m, __shfl_xor(m, 8));
    float s = 0.0f;
    #pragma unroll
    for (int x = 0; x < 8; ++x) s += __expf(sv[x] - m);
    s += __shfl_xor(s, 1);
    s += __shfl_xor(s, 2);
    s += __shfl_xor(s, 4);
    s += __shfl_xor(s, 8);
    const int row = ig*4 + r;
    *(float4*)&Sb[(size_t)row*NLQ + jg*8]     = make_float4(sv[0],sv[1],sv[2],sv[3]);
    *(float4*)&Sb[(size_t)row*NLQ + jg*8 + 4] = make_float4(sv[4],sv[5],sv[6],sv[7]);
    if (jg == 0) {
      ws[OFF_RMAX + (size_t)b*NLC + i0 + row] = m;
      ws[OFF_RSUM + (size_t)b*NLC + i0 + row] = 1.0f / s;
    }
  }
}

// ============ column softmax stats over i (axis=1): cmax, 1/csum ============
__global__ __launch_bounds__(256) void k_colstats(float* __restrict__ ws) {
  __shared__ float red[8][32];
  const int b  = blockIdx.y;
  const int jq = blockIdx.x;            // 4 j-quarters of 32
  const int tx = threadIdx.x & 31;
  const int ty = threadIdx.x >> 5;      // 8 i-strips of 128
  const int j  = jq*32 + tx;
  const float* Sb = ws + OFF_S + (size_t)b*NLC*NLQ;
  float m = -3.0e38f;
  for (int ii = 0; ii < 128; ++ii)
    m = fmaxf(m, Sb[(size_t)(ty*128 + ii)*NLQ + j]);
  red[ty][tx] = m;
  __syncthreads();
  if (ty == 0) {
    #pragma unroll
    for (int y = 1; y < 8; ++y) m = fmaxf(m, red[y][tx]);
    red[0][tx] = m;
  }
  __syncthreads();
  const float cm = red[0][tx];
  __syncthreads();
  float s = 0.0f;
  for (int ii = 0; ii < 128; ++ii)
    s += __expf(Sb[(size_t)(ty*128 + ii)*NLQ + j] - cm);
  red[ty][tx] = s;
  __syncthreads();
  if (ty == 0) {
    #pragma unroll
    for (int y = 1; y < 8; ++y) s += red[y][tx];
    ws[OFF_CMAX + (size_t)b*NLQ + j] = cm;
    ws[OFF_CSUM + (size_t)b*NLQ + j] = 1.0f / s;
  }
}

// ======= M[b,d,j] = sum_k C[b,d,k] * S__[b,k,j]  (split-K=2, d-split=4) =====
// grid (8, NB): blockIdx.x = dq(4) x ksp(2) -> 512 blocks = 2/CU.
__global__ __launch_bounds__(256) void k_m(const float* __restrict__ C,
                                           float* __restrict__ ws) {
  __shared__ float Ps[32][128];
  __shared__ float Csh[32][68];         // [kk][d-local], padded
  __shared__ float cmS[128], icS[128];
  const int b   = blockIdx.y;
  const int dq  = blockIdx.x & 3;       // d quarter: 64 rows
  const int ksp = blockIdx.x >> 2;      // k split: 512 each
  const int t   = threadIdx.x;
  const int jg  = t & 15;               // j = jg*8..+7
  const int dg  = t >> 4;               // d = dq*64 + dg*4..+3
  if (t < 128) {
    cmS[t] = ws[OFF_CMAX + (size_t)b*NLQ + t];
    icS[t] = ws[OFF_CSUM + (size_t)b*NLQ + t];   // reciprocal
  }
  float acc[4][8];
  #pragma unroll
  for (int r = 0; r < 4; ++r)
    #pragma unroll
    for (int x = 0; x < 8; ++x) acc[r][x] = 0.0f;

  const float* Cb = C + (size_t)b*ND*NLC + (size_t)dq*64*NLC;
  const float* Sb = ws + OFF_S + (size_t)b*NLC*NLQ;
  const int kbase = ksp * 512;

  for (int kt = 0; kt < 16; ++kt) {
    const int k0 = kbase + kt*32;
    __syncthreads();
    #pragma unroll
    for (int r = 0; r < 4; ++r) {       // stage S__ tile, exp applied
      const int f = r*256 + t;
      const int kk = f >> 5, j4 = f & 31;
      const float4 sv = *(const float4*)&Sb[(size_t)(k0+kk)*NLQ + j4*4];
      const int j = j4*4;
      float4 p;
      p.x = __expf(sv.x - cmS[j+0]) * icS[j+0];
      p.y = __expf(sv.y - cmS[j+1]) * icS[j+1];
      p.z = __expf(sv.z - cmS[j+2]) * icS[j+2];
      p.w = __expf(sv.w - cmS[j+3]) * icS[j+3];
      *(float4*)&Ps[kk][j4*4] = p;
    }
    #pragma unroll
    for (int r = 0; r < 2; ++r) {       // stage C transposed -> [kk][d] (64 d)
      const int f = r*256 + t;
      const int kq = f & 7, dl = f >> 3;
      const float4 cv = *(const float4*)&Cb[(size_t)dl*NLC + k0 + kq*4];
      Csh[kq*4+0][dl] = cv.x;
      Csh[kq*4+1][dl] = cv.y;
      Csh[kq*4+2][dl] = cv.z;
      Csh[kq*4+3][dl] = cv.w;
    }
    __syncthreads();
    #pragma unroll
    for (int kk = 0; kk < 32; ++kk) {
      const float4 c4 = *(const float4*)&Csh[kk][dg*4];
      const float4 p0 = *(const float4*)&Ps[kk][jg*8];
      const float4 p1 = *(const float4*)&Ps[kk][jg*8+4];
      const float cr[4] = {c4.x,c4.y,c4.z,c4.w};
      const float pv[8] = {p0.x,p0.y,p0.z,p0.w,p1.x,p1.y,p1.z,p1.w};
      #pragma unroll
      for (int r = 0; r < 4; ++r)
        #pragma unroll
        for (int x = 0; x < 8; ++x)
          acc[r][x] = fmaf(cr[r], pv[x], acc[r][x]);
    }
  }
  float* Mp = ws + OFF_M + ((size_t)ksp*NB + b)*ND*NLQ + (size_t)dq*64*NLQ;
  #pragma unroll
  for (int r = 0; r < 4; ++r) {
    const int d = dg*4 + r;
    *(float4*)&Mp[(size_t)d*NLQ + jg*8]     = make_float4(acc[r][0],acc[r][1],acc[r][2],acc[r][3]);
    *(float4*)&Mp[(size_t)d*NLQ + jg*8 + 4] = make_float4(acc[r][4],acc[r][5],acc[r][6],acc[r][7]);
  }
}

// ==== final: A = Q*S_^T, Bm = M*S_^T, write [C, A, C*A, C*Bm] w/ dropout ====
// bf16 LDS tiles: 34+16+16 = 66 KiB -> 2 blocks/CU (was 128 KiB, 1 block/CU).
__global__ __launch_bounds__(256, 2) void k_final(const float* __restrict__ C,
                                                  const float* __restrict__ Q,
                                                  float* __restrict__ ws,
                                                  float* __restrict__ out) {
  __shared__ alignas(16) ushort St[128][136];   // [j][i]  S_ bf16
  __shared__ alignas(16) ushort Qt[128][64];    // [j][d]  bf16
  __shared__ alignas(16) ushort Mt[128][64];    // [j][d]  bf16, M0+M1
  const int b  = blockIdx.z;
  const int i0 = blockIdx.x * 128;
  const int d0 = blockIdx.y * 64;
  const int t  = threadIdx.x;
  const int ig = t & 15;                // i = i0 + ig*8 .. +7
  const int dg = t >> 4;                // d = d0 + dg*4 .. +3

  const float* Sb  = ws + OFF_S + ((size_t)b*NLC + (size_t)i0)*NLQ;
  const float* rmp = ws + OFF_RMAX + (size_t)b*NLC + i0;
  const float* irp = ws + OFF_RSUM + (size_t)b*NLC + i0;
  #pragma unroll
  for (int r = 0; r < 16; ++r) {        // stage S_ transposed (coalesced rows)
    const int f  = r*256 + t;
    const int j4 = f & 31;              // j = j4*4 .. +3
    const int il = f >> 5;              // 0..127
    const float4 sv = *(const float4*)&Sb[(size_t)il*NLQ + j4*4];
    const float rm = rmp[il];
    const float ir = irp[il];
    St[j4*4+0][il] = (ushort)f2bf(__expf(sv.x - rm) * ir);
    St[j4*4+1][il] = (ushort)f2bf(__expf(sv.y - rm) * ir);
    St[j4*4+2][il] = (ushort)f2bf(__expf(sv.z - rm) * ir);
    St[j4*4+3][il] = (ushort)f2bf(__expf(sv.w - rm) * ir);
  }
  const float* Qb  = Q + (size_t)b*ND*NLQ + (size_t)d0*NLQ;
  const float* M0p = ws + OFF_M + (size_t)b*ND*NLQ + (size_t)d0*NLQ;
  const float* M1p = M0p + (size_t)NB*ND*NLQ;
  #pragma unroll
  for (int r = 0; r < 8; ++r) {         // stage Q, M transposed (coalesced rows)
    const int f  = r*256 + t;
    const int j4 = f & 31;              // j = j4*4 .. +3
    const int dl = f >> 5;              // 0..63
    const float4 qv = *(const float4*)&Qb[(size_t)dl*NLQ + j4*4];
    Qt[j4*4+0][dl] = (ushort)f2bf(qv.x);
    Qt[j4*4+1][dl] = (ushort)f2bf(qv.y);
    Qt[j4*4+2][dl] = (ushort)f2bf(qv.z);
    Qt[j4*4+3][dl] = (ushort)f2bf(qv.w);
    const float4 m0 = *(const float4*)&M0p[(size_t)dl*NLQ + j4*4];
    const float4 m1 = *(const float4*)&M1p[(size_t)dl*NLQ + j4*4];
    Mt[j4*4+0][dl] = (ushort)f2bf(m0.x + m1.x);
    Mt[j4*4+1][dl] = (ushort)f2bf(m0.y + m1.y);
    Mt[j4*4+2][dl] = (ushort)f2bf(m0.z + m1.z);
    Mt[j4*4+3][dl] = (ushort)f2bf(m0.w + m1.w);
  }
  __syncthreads();

  float accA[4][8], accB[4][8];
  #pragma unroll
  for (int r = 0; r < 4; ++r)
    #pragma unroll
    for (int x = 0; x < 8; ++x) { accA[r][x] = 0.0f; accB[r][x] = 0.0f; }

  #pragma unroll 2
  for (int j = 0; j < 128; ++j) {
    const uint4 su = *(const uint4*)&St[j][ig*8];
    const uint2 qu = *(const uint2*)&Qt[j][dg*4];
    const uint2 mu = *(const uint2*)&Mt[j][dg*4];
    const float sv[8] = {bflo(su.x),bfhi(su.x),bflo(su.y),bfhi(su.y),
                         bflo(su.z),bfhi(su.z),bflo(su.w),bfhi(su.w)};
    const float qv[4] = {bflo(qu.x),bfhi(qu.x),bflo(qu.y),bfhi(qu.y)};
    const float mv[4] = {bflo(mu.x),bfhi(mu.x),bflo(mu.y),bfhi(mu.y)};
    #pragma unroll
    for (int r = 0; r < 4; ++r)
      #pragma unroll
      for (int x = 0; x < 8; ++x) {
        accA[r][x] = fmaf(qv[r], sv[x], accA[r][x]);
        accB[r][x] = fmaf(mv[r], sv[x], accB[r][x]);
      }
  }

  const float* Cb = C + (size_t)b*ND*NLC;
  const uint32_t* mw = (const uint32_t*)(ws + OFF_MASK);
  #pragma unroll
  for (int r = 0; r < 4; ++r) {
    const int d = d0 + dg*4 + r;
    const int i = i0 + ig*8;
    const float4 cc0 = *(const float4*)&Cb[(size_t)d*NLC + i];
    const float4 cc1 = *(const float4*)&Cb[(size_t)d*NLC + i + 4];
    const float cv[8] = {cc0.x,cc0.y,cc0.z,cc0.w,cc1.x,cc1.y,cc1.z,cc1.w};
    #pragma unroll
    for (int s = 0; s < 4; ++s) {
      const uint32_t ch = (uint32_t)(s*ND + d);
      const uint32_t nbase = ((((uint32_t)b << 10) + ch) << 10) + (uint32_t)i;
      const uint32_t wbits = mw[nbase >> 5];
      const uint32_t sh = nbase & 31u;
      float ov[8];
      #pragma unroll
      for (int x = 0; x < 8; ++x) {
        float v;
        if (s == 0)      v = cv[x];
        else if (s == 1) v = accA[r][x];
        else if (s == 2) v = cv[x] * accA[r][x];
        else             v = cv[x] * accB[r][x];
        ov[x] = ((wbits >> (sh + (uint32_t)x)) & 1u) ? v * INVKEEP : 0.0f;
      }
      *(float4*)&out[nbase]     = make_float4(ov[0],ov[1],ov[2],ov[3]);
      *(float4*)&out[nbase + 4] = make_float4(ov[4],ov[5],ov[6],ov[7]);
    }
  }
}

extern "C" void kernel_launch(void* const* d_in, const int* in_sizes, int n_in,
                              void* d_out, int out_size, void* d_ws, size_t ws_size,
                              hipStream_t stream) {
  (void)in_sizes; (void)n_in; (void)out_size; (void)ws_size;
  const float* C = (const float*)d_in[0];
  const float* Q = (const float*)d_in[1];
  const float* W = (const float*)d_in[2];
  float* out = (float*)d_out;
  float* ws  = (float*)d_ws;
  uint32_t* mask = (uint32_t*)(ws + OFF_MASK);

  hipLaunchKernelGGL(k_sq,       dim3(NB),       dim3(128), 0, stream, Q, W, ws);
  hipLaunchKernelGGL(k_mask,     dim3(8192),     dim3(256), 0, stream, mask);
  hipLaunchKernelGGL(k_s,        dim3(16, NB),   dim3(256), 0, stream, C, Q, W, ws);
  hipLaunchKernelGGL(k_colstats, dim3(4, NB),    dim3(256), 0, stream, ws);
  hipLaunchKernelGGL(k_m,        dim3(8, NB),    dim3(256), 0, stream, C, ws);
  hipLaunchKernelGGL(k_final,    dim3(8, 4, NB), dim3(256), 0, stream, C, Q, ws, out);
}

// Round 4
// 451.721 us; speedup vs baseline: 1.1600x; 1.0870x over previous
//
#include <hip/hip_runtime.h>
#include <stdint.h>
#include <stddef.h>

#define NB  64
#define ND  256
#define NLC 1024
#define NLQ 128
#define INVKEEP (1.0f/0.9f)

// ---- workspace layout (float offsets) ----
#define OFF_SQ    0u            // NB*NLQ
#define OFF_RMAX  8192u         // NB*NLC  (row max of S)
#define OFF_RSUM  73728u        // NB*NLC  (RECIPROCAL row sum)
#define OFF_CMAX  139264u       // NB*NLQ  (col max)
#define OFF_CSUM  147456u       // NB*NLQ  (RECIPROCAL col sum)
#define OFF_S     155648u       // NB*NLC*NLQ (raw S)
#define OFF_M     8544256u      // 2*NB*ND*NLQ (split-K partial M)
#define OFF_MASK  12738560u     // dropout bitmask u32 words

typedef float f32x4  __attribute__((ext_vector_type(4)));
typedef short bf16x8 __attribute__((ext_vector_type(8)));

// bf16 helpers: RNE pack
__device__ __forceinline__ uint32_t f2bf(float x) {
  const uint32_t u = __float_as_uint(x);
  return (u + 0x7fffu + ((u >> 16) & 1u)) >> 16;
}

// ================= threefry2x32, key=(0,42); bits = o0^o1 (verified r2) =====
__device__ __forceinline__ void tf_round(uint32_t& a, uint32_t& b, const int r) {
  a += b;
  b = (b << r) | (b >> (32 - r));
  b ^= a;
}
__device__ __forceinline__ uint32_t threefry_xor(uint32_t x0, uint32_t x1) {
  const uint32_t ks0 = 0u, ks1 = 42u, ks2 = 0x1BD11BDAu ^ 0u ^ 42u;
  x0 += ks0; x1 += ks1;
  tf_round(x0,x1,13); tf_round(x0,x1,15); tf_round(x0,x1,26); tf_round(x0,x1,6);
  x0 += ks1; x1 += ks2 + 1u;
  tf_round(x0,x1,17); tf_round(x0,x1,29); tf_round(x0,x1,16); tf_round(x0,x1,24);
  x0 += ks2; x1 += ks0 + 2u;
  tf_round(x0,x1,13); tf_round(x0,x1,15); tf_round(x0,x1,26); tf_round(x0,x1,6);
  x0 += ks0; x1 += ks1 + 3u;
  tf_round(x0,x1,17); tf_round(x0,x1,29); tf_round(x0,x1,16); tf_round(x0,x1,24);
  x0 += ks1; x1 += ks2 + 4u;
  tf_round(x0,x1,13); tf_round(x0,x1,15); tf_round(x0,x1,26); tf_round(x0,x1,6);
  x0 += ks2; x1 += ks0 + 5u;
  return x0 ^ x1;
}

__global__ __launch_bounds__(256) void k_mask(uint32_t* __restrict__ mask) {
  const uint32_t t = blockIdx.x * 256u + threadIdx.x;
  const uint32_t base = t << 5;
  uint32_t w = 0u;
  #pragma unroll 4
  for (int k = 0; k < 32; ++k) {
    const uint32_t bits = threefry_xor(0u, base + (uint32_t)k);
    const float u = __uint_as_float((bits >> 9) | 0x3f800000u) - 1.0f;
    w |= (u < 0.9f ? 1u : 0u) << k;
  }
  mask[t] = w;
}

// ================= sq[b,j] = sum_d wq[d] * Q[b,d,j] ==========================
__global__ __launch_bounds__(128) void k_sq(const float* __restrict__ Q,
                                            const float* __restrict__ W,
                                            float* __restrict__ ws) {
  const int b = blockIdx.x;
  const int j = threadIdx.x;
  const float* wq = W + (size_t)b*768;
  const float* Qb = Q + (size_t)b*ND*NLQ;
  float acc = 0.0f;
  for (int d = 0; d < ND; ++d) acc = fmaf(wq[d], Qb[(size_t)d*NLQ + j], acc);
  ws[OFF_SQ + (size_t)b*NLQ + j] = acc;
}

// ========== S[b,i,j] = sum_d C[d,i]*(wm[d]*Q[d,j]+wc[d]) + sq[j] ============
__global__ __launch_bounds__(256) void k_s(const float* __restrict__ C,
                                           const float* __restrict__ Q,
                                           const float* __restrict__ W,
                                           float* __restrict__ ws) {
  __shared__ float Cs[32][64];
  __shared__ float Qs[32][128];
  __shared__ float wmS[256], wcS[256], sqS[128];
  const int b  = blockIdx.y;
  const int i0 = blockIdx.x * 64;
  const int t  = threadIdx.x;
  const int jg = t & 15;        // j = jg*8 .. +7
  const int ig = t >> 4;        // i = i0 + ig*4 .. +3
  wcS[t] = W[(size_t)b*768 + 256 + t];
  wmS[t] = W[(size_t)b*768 + 512 + t];
  if (t < 128) sqS[t] = ws[OFF_SQ + (size_t)b*NLQ + t];

  float acc[4][8];
  #pragma unroll
  for (int r = 0; r < 4; ++r)
    #pragma unroll
    for (int x = 0; x < 8; ++x) acc[r][x] = 0.0f;

  const float* Cb = C + (size_t)b*ND*NLC;
  const float* Qb = Q + (size_t)b*ND*NLQ;

  for (int d0 = 0; d0 < ND; d0 += 32) {
    __syncthreads();
    #pragma unroll
    for (int r = 0; r < 2; ++r) {
      const int f = r*256 + t;
      const int dk = f >> 4, i4 = f & 15;
      *(float4*)&Cs[dk][i4*4] = *(const float4*)&Cb[(size_t)(d0+dk)*NLC + i0 + i4*4];
    }
    #pragma unroll
    for (int r = 0; r < 4; ++r) {
      const int f = r*256 + t;
      const int dk = f >> 5, j4 = f & 31;
      const float4 qv = *(const float4*)&Qb[(size_t)(d0+dk)*NLQ + j4*4];
      const float wmv = wmS[d0+dk], wcv = wcS[d0+dk];
      float4 o;
      o.x = fmaf(wmv, qv.x, wcv);
      o.y = fmaf(wmv, qv.y, wcv);
      o.z = fmaf(wmv, qv.z, wcv);
      o.w = fmaf(wmv, qv.w, wcv);
      *(float4*)&Qs[dk][j4*4] = o;
    }
    __syncthreads();
    #pragma unroll
    for (int dk = 0; dk < 32; ++dk) {
      const float4 cq = *(const float4*)&Cs[dk][ig*4];
      const float4 q0 = *(const float4*)&Qs[dk][jg*8];
      const float4 q1 = *(const float4*)&Qs[dk][jg*8+4];
      const float cr[4] = {cq.x, cq.y, cq.z, cq.w};
      const float qv[8] = {q0.x,q0.y,q0.z,q0.w,q1.x,q1.y,q1.z,q1.w};
      #pragma unroll
      for (int r = 0; r < 4; ++r)
        #pragma unroll
        for (int x = 0; x < 8; ++x)
          acc[r][x] = fmaf(cr[r], qv[x], acc[r][x]);
    }
  }

  float sqv[8];
  #pragma unroll
  for (int x = 0; x < 8; ++x) sqv[x] = sqS[jg*8 + x];
  float* Sb = ws + OFF_S + ((size_t)b*NLC + (size_t)i0)*NLQ;
  #pragma unroll
  for (int r = 0; r < 4; ++r) {
    float sv[8];
    #pragma unroll
    for (int x = 0; x < 8; ++x) sv[x] = acc[r][x] + sqv[x];
    float m = sv[0];
    #pragma unroll
    for (int x = 1; x < 8; ++x) m = fmaxf(m, sv[x]);
    m = fmaxf(m, __shfl_xor(m, 1));
    m = fmaxf(m, __shfl_xor(m, 2));
    m = fmaxf(m, __shfl_xor(m, 4));
    m = fmaxf(m, __shfl_xor(m, 8));
    float s = 0.0f;
    #pragma unroll
    for (int x = 0; x < 8; ++x) s += __expf(sv[x] - m);
    s += __shfl_xor(s, 1);
    s += __shfl_xor(s, 2);
    s += __shfl_xor(s, 4);
    s += __shfl_xor(s, 8);
    const int row = ig*4 + r;
    *(float4*)&Sb[(size_t)row*NLQ + jg*8]     = make_float4(sv[0],sv[1],sv[2],sv[3]);
    *(float4*)&Sb[(size_t)row*NLQ + jg*8 + 4] = make_float4(sv[4],sv[5],sv[6],sv[7]);
    if (jg == 0) {
      ws[OFF_RMAX + (size_t)b*NLC + i0 + row] = m;
      ws[OFF_RSUM + (size_t)b*NLC + i0 + row] = 1.0f / s;
    }
  }
}

// ============ column softmax stats over i (axis=1): cmax, 1/csum ============
__global__ __launch_bounds__(256) void k_colstats(float* __restrict__ ws) {
  __shared__ float red[8][32];
  const int b  = blockIdx.y;
  const int jq = blockIdx.x;
  const int tx = threadIdx.x & 31;
  const int ty = threadIdx.x >> 5;
  const int j  = jq*32 + tx;
  const float* Sb = ws + OFF_S + (size_t)b*NLC*NLQ;
  float m = -3.0e38f;
  for (int ii = 0; ii < 128; ++ii)
    m = fmaxf(m, Sb[(size_t)(ty*128 + ii)*NLQ + j]);
  red[ty][tx] = m;
  __syncthreads();
  if (ty == 0) {
    #pragma unroll
    for (int y = 1; y < 8; ++y) m = fmaxf(m, red[y][tx]);
    red[0][tx] = m;
  }
  __syncthreads();
  const float cm = red[0][tx];
  __syncthreads();
  float s = 0.0f;
  for (int ii = 0; ii < 128; ++ii)
    s += __expf(Sb[(size_t)(ty*128 + ii)*NLQ + j] - cm);
  red[ty][tx] = s;
  __syncthreads();
  if (ty == 0) {
    #pragma unroll
    for (int y = 1; y < 8; ++y) s += red[y][tx];
    ws[OFF_CMAX + (size_t)b*NLQ + j] = cm;
    ws[OFF_CSUM + (size_t)b*NLQ + j] = 1.0f / s;
  }
}

// ======= M[b,d,j] = sum_k C[b,d,k] * S__[b,k,j]  (split-K=2, d-split=4) =====
// 1D grid 512, XCD-grouped: the 4 dq-blocks of one (ksp,b) share an XCD L2
// so the S half-slab (256 KB) is fetched ~once per group.
__global__ __launch_bounds__(256) void k_m(const float* __restrict__ C,
                                           float* __restrict__ ws) {
  __shared__ float Ps[32][128];
  __shared__ float Csh[32][68];
  __shared__ float cmS[128], icS[128];
  const int n   = blockIdx.x;
  const int rr  = n & 7, qq = n >> 3;
  const int dq  = qq & 3;               // member: d quarter
  const int g   = (qq >> 2) * 8 + rr;   // group 0..127 = (ksp,b)
  const int b   = g & 63;
  const int ksp = g >> 6;
  const int t   = threadIdx.x;
  const int jg  = t & 15;
  const int dg  = t >> 4;
  if (t < 128) {
    cmS[t] = ws[OFF_CMAX + (size_t)b*NLQ + t];
    icS[t] = ws[OFF_CSUM + (size_t)b*NLQ + t];
  }
  float acc[4][8];
  #pragma unroll
  for (int r = 0; r < 4; ++r)
    #pragma unroll
    for (int x = 0; x < 8; ++x) acc[r][x] = 0.0f;

  const float* Cb = C + (size_t)b*ND*NLC + (size_t)dq*64*NLC;
  const float* Sb = ws + OFF_S + (size_t)b*NLC*NLQ;
  const int kbase = ksp * 512;

  for (int kt = 0; kt < 16; ++kt) {
    const int k0 = kbase + kt*32;
    __syncthreads();
    #pragma unroll
    for (int r = 0; r < 4; ++r) {
      const int f = r*256 + t;
      const int kk = f >> 5, j4 = f & 31;
      const float4 sv = *(const float4*)&Sb[(size_t)(k0+kk)*NLQ + j4*4];
      const int j = j4*4;
      float4 p;
      p.x = __expf(sv.x - cmS[j+0]) * icS[j+0];
      p.y = __expf(sv.y - cmS[j+1]) * icS[j+1];
      p.z = __expf(sv.z - cmS[j+2]) * icS[j+2];
      p.w = __expf(sv.w - cmS[j+3]) * icS[j+3];
      *(float4*)&Ps[kk][j4*4] = p;
    }
    #pragma unroll
    for (int r = 0; r < 2; ++r) {
      const int f = r*256 + t;
      const int kq = f & 7, dl = f >> 3;
      const float4 cv = *(const float4*)&Cb[(size_t)dl*NLC + k0 + kq*4];
      Csh[kq*4+0][dl] = cv.x;
      Csh[kq*4+1][dl] = cv.y;
      Csh[kq*4+2][dl] = cv.z;
      Csh[kq*4+3][dl] = cv.w;
    }
    __syncthreads();
    #pragma unroll
    for (int kk = 0; kk < 32; ++kk) {
      const float4 c4 = *(const float4*)&Csh[kk][dg*4];
      const float4 p0 = *(const float4*)&Ps[kk][jg*8];
      const float4 p1 = *(const float4*)&Ps[kk][jg*8+4];
      const float cr[4] = {c4.x,c4.y,c4.z,c4.w};
      const float pv[8] = {p0.x,p0.y,p0.z,p0.w,p1.x,p1.y,p1.z,p1.w};
      #pragma unroll
      for (int r = 0; r < 4; ++r)
        #pragma unroll
        for (int x = 0; x < 8; ++x)
          acc[r][x] = fmaf(cr[r], pv[x], acc[r][x]);
    }
  }
  float* Mp = ws + OFF_M + ((size_t)ksp*NB + b)*ND*NLQ + (size_t)dq*64*NLQ;
  #pragma unroll
  for (int r = 0; r < 4; ++r) {
    const int d = dg*4 + r;
    *(float4*)&Mp[(size_t)d*NLQ + jg*8]     = make_float4(acc[r][0],acc[r][1],acc[r][2],acc[r][3]);
    *(float4*)&Mp[(size_t)d*NLQ + jg*8 + 4] = make_float4(acc[r][4],acc[r][5],acc[r][6],acc[r][7]);
  }
}

// ==== final (MFMA): A = Q*S_^T, Bm = M*S_^T, out = [C, A, C*A, C*Bm] ========
// Natural-layout bf16 LDS tiles (St[i][j], Qt/Mt[d][j]) — no transpose needed
// because the 16x16x32 B-fragment reads k-contiguous per lane. XOR swizzle
// col ^= (row&7)<<3 (16B granule) makes fragment reads conflict-free.
// 1D grid 2048, XCD-grouped: 4 d-blocks of one (i0,b) share an XCD L2.
__global__ __launch_bounds__(256, 2) void k_final(const float* __restrict__ C,
                                                  const float* __restrict__ Q,
                                                  float* __restrict__ ws,
                                                  float* __restrict__ out) {
  __shared__ ushort St[128][128];       // [i][j] bf16, swizzled
  __shared__ ushort Qt[64][128];        // [d][j] bf16, swizzled
  __shared__ ushort Mt[64][128];        // [d][j] bf16 (M0+M1), swizzled
  const int n  = blockIdx.x;
  const int rr = n & 7, qq = n >> 3;
  const int m  = qq & 3;                // member: d0 block
  const int g  = (qq >> 2) * 8 + rr;    // group 0..511 = (i0,b)
  const int b  = g & 63;
  const int i0 = (g >> 6) * 128;
  const int d0 = m * 64;
  const int t  = threadIdx.x;

  // --- stage S_ (row-softmax applied) as bf16 rows ---
  const float* Sb  = ws + OFF_S + ((size_t)b*NLC + (size_t)i0)*NLQ;
  const float* rmp = ws + OFF_RMAX + (size_t)b*NLC + i0;
  const float* irp = ws + OFF_RSUM + (size_t)b*NLC + i0;
  #pragma unroll
  for (int p = 0; p < 16; ++p) {
    const int f  = p*256 + t;
    const int j4 = f & 31;              // 4 consecutive j
    const int il = f >> 5;              // row 0..127
    const float4 sv = *(const float4*)&Sb[(size_t)il*NLQ + j4*4];
    const float rm = rmp[il], ir = irp[il];
    uint2 pk;
    pk.x = f2bf(__expf(sv.x - rm) * ir) | (f2bf(__expf(sv.y - rm) * ir) << 16);
    pk.y = f2bf(__expf(sv.z - rm) * ir) | (f2bf(__expf(sv.w - rm) * ir) << 16);
    *(uint2*)&St[il][(j4*4) ^ ((il & 7) << 3)] = pk;
  }
  // --- stage Q and M (=M0+M1) as bf16 rows ---
  const float* Qb  = Q + (size_t)b*ND*NLQ + (size_t)d0*NLQ;
  const float* M0p = ws + OFF_M + (size_t)b*ND*NLQ + (size_t)d0*NLQ;
  const float* M1p = M0p + (size_t)NB*ND*NLQ;
  #pragma unroll
  for (int p = 0; p < 8; ++p) {
    const int f  = p*256 + t;
    const int j4 = f & 31;
    const int dl = f >> 5;              // row 0..63
    const int col = (j4*4) ^ ((dl & 7) << 3);
    const float4 qv = *(const float4*)&Qb[(size_t)dl*NLQ + j4*4];
    uint2 pq;
    pq.x = f2bf(qv.x) | (f2bf(qv.y) << 16);
    pq.y = f2bf(qv.z) | (f2bf(qv.w) << 16);
    *(uint2*)&Qt[dl][col] = pq;
    const float4 m0 = *(const float4*)&M0p[(size_t)dl*NLQ + j4*4];
    const float4 m1 = *(const float4*)&M1p[(size_t)dl*NLQ + j4*4];
    uint2 pm;
    pm.x = f2bf(m0.x + m1.x) | (f2bf(m0.y + m1.y) << 16);
    pm.y = f2bf(m0.z + m1.z) | (f2bf(m0.w + m1.w) << 16);
    *(uint2*)&Mt[dl][col] = pm;
  }
  __syncthreads();

  // --- MFMA main loop: wave w owns d-rows [w*16, w*16+16) ---
  const int w  = t >> 6;
  const int l  = t & 63;
  const int lm = l & 15;                // 16-dim index (m for A, n for B/D)
  const int lk = (l >> 4) * 8;          // k sub-offset
  const int sw = (lm & 7) << 3;         // row-swizzle (row&7 == lm&7 everywhere)

  f32x4 accA[8], accB[8];
  #pragma unroll
  for (int f = 0; f < 8; ++f) { accA[f] = (f32x4)0.0f; accB[f] = (f32x4)0.0f; }

  #pragma unroll
  for (int ks = 0; ks < 4; ++ks) {
    const int koff = (ks*32 + lk) ^ sw;
    const bf16x8 qf = *(const bf16x8*)&Qt[w*16 + lm][koff];
    const bf16x8 mf = *(const bf16x8*)&Mt[w*16 + lm][koff];
    #pragma unroll
    for (int f = 0; f < 8; ++f) {
      const bf16x8 sf = *(const bf16x8*)&St[f*16 + lm][koff];
      accA[f] = __builtin_amdgcn_mfma_f32_16x16x32_bf16(qf, sf, accA[f], 0, 0, 0);
      accB[f] = __builtin_amdgcn_mfma_f32_16x16x32_bf16(mf, sf, accB[f], 0, 0, 0);
    }
  }

  // --- epilogue: D frag layout col(=i)=lane&15, row(=d)=(lane>>4)*4+reg ---
  const float* Cb = C + (size_t)b*ND*NLC;
  const uint32_t* mw = (const uint32_t*)(ws + OFF_MASK);
  const int dbase = d0 + w*16 + (l >> 4)*4;
  #pragma unroll
  for (int f = 0; f < 8; ++f) {
    const int i = i0 + f*16 + lm;
    #pragma unroll
    for (int r = 0; r < 4; ++r) {
      const int d = dbase + r;
      const float c = Cb[(size_t)d*NLC + i];
      const float a  = accA[f][r];
      const float bm = accB[f][r];
      const float vals[4] = {c, a, c*a, c*bm};
      #pragma unroll
      for (int s = 0; s < 4; ++s) {
        const uint32_t nb = ((((uint32_t)b << 10) + (uint32_t)(s*ND + d)) << 10)
                            + (uint32_t)i;
        const uint32_t wb = mw[nb >> 5];
        out[nb] = ((wb >> (nb & 31u)) & 1u) ? vals[s] * INVKEEP : 0.0f;
      }
    }
  }
}

extern "C" void kernel_launch(void* const* d_in, const int* in_sizes, int n_in,
                              void* d_out, int out_size, void* d_ws, size_t ws_size,
                              hipStream_t stream) {
  (void)in_sizes; (void)n_in; (void)out_size; (void)ws_size;
  const float* C = (const float*)d_in[0];
  const float* Q = (const float*)d_in[1];
  const float* W = (const float*)d_in[2];
  float* out = (float*)d_out;
  float* ws  = (float*)d_ws;
  uint32_t* mask = (uint32_t*)(ws + OFF_MASK);

  hipLaunchKernelGGL(k_sq,       dim3(NB),     dim3(128), 0, stream, Q, W, ws);
  hipLaunchKernelGGL(k_mask,     dim3(8192),   dim3(256), 0, stream, mask);
  hipLaunchKernelGGL(k_s,        dim3(16, NB), dim3(256), 0, stream, C, Q, W, ws);
  hipLaunchKernelGGL(k_colstats, dim3(4, NB),  dim3(256), 0, stream, ws);
  hipLaunchKernelGGL(k_m,        dim3(512),    dim3(256), 0, stream, C, ws);
  hipLaunchKernelGGL(k_final,    dim3(2048),   dim3(256), 0, stream, C, Q, ws, out);
}